// Round 2
// baseline (1738.980 us; speedup 1.0000x reference)
//
#include <hip/hip_runtime.h>

#define D_    256
#define V_    32
#define HW_   (512*512)
#define OUTF_ 256

// padded leading dim for the Q LDS tile: rows 16B-aligned (36*4=144=9*16),
// and tid*36 spreads the per-thread float4 row-writes across all 32 banks.
#define QS_LD 36

// ---------------------------------------------------------------------------
// K12 (fused k1+k2): both old kernels streamed all of X (268 MB each) over
// the SAME 512-pixel blocks. Fused: phase 1 computes Q + softmax (X read #1),
// keeps Q rows in LDS; phase 3 re-reads the block's 512KB X slice (L3-hot,
// ~30us after first touch) and accumulates M[d,i] = sum_p X[p,d]*Q[p,i].
//
// Latency fix (the actual round-1 lesson): old k2 ran at MLP=1 (~1018 cyc per
// pixel-iteration == 1 HBM miss). Here the x values are prefetched into NAMED
// register arrays, double-buffered: 16 loads issue as a batch while the
// previous 16 pixels' 1024 cycles of FMAs retire -> latency fully hidden.
// Same for phase 1 (4 float4/row groups, 2KB/wave in flight).
// ---------------------------------------------------------------------------
__global__ __launch_bounds__(256) void k12_fused(const float* __restrict__ X,
                                                 const float* __restrict__ W,
                                                 const float* __restrict__ var,
                                                 float* __restrict__ Q,
                                                 float* __restrict__ s_out,
                                                 float* __restrict__ M)
{
    __shared__ float smem[512 * QS_LD];   // 73.7 KB: As/Bs in phase 1, Qs in phase 3
    __shared__ float s_blk[V_];
    float* As = smem;                     // [256][32]  W*iv
    float* Bs = smem + D_ * V_;           // [256][32]  iv

    const int tid = threadIdx.x;

    // ---- setup: As/Bs (thread t = row d), s_blk init
    {
        const float* wr = W   + tid * V_;
        const float* vr = var + tid * V_;
        #pragma unroll
        for (int i = 0; i < V_; ++i) {
            float iv = 1.0f / vr[i];
            As[tid * V_ + i] = wr[i] * iv;
            Bs[tid * V_ + i] = iv;
        }
    }
    if (tid < V_) s_blk[tid] = 0.f;
    __syncthreads();

    const size_t p0 = (size_t)blockIdx.x * 512;
    const size_t pA = p0 + tid;
    const size_t pB = pA + 256;

    // ================= phase 1: Q logits (two pixels per thread) ===========
    const float4* xrA = (const float4*)(X + pA * D_);
    const float4* xrB = (const float4*)(X + pB * D_);

    float tA[V_], tB[V_];
    #pragma unroll
    for (int i = 0; i < V_; ++i) { tA[i] = 0.f; tB[i] = 0.f; }

    // register double-buffer: 4 float4 per row in flight (2KB/wave), compute
    // per group = 16 d * 32 i * 4 ops = 4096 cyc >> 900 cyc HBM latency.
    float4 cA[4], cB[4], nA[4], nB[4];
    #pragma unroll
    for (int k = 0; k < 4; ++k) { cA[k] = xrA[k]; cB[k] = xrB[k]; }

    for (int g = 0; g < 16; ++g) {
        if (g < 15) {
            #pragma unroll
            for (int k = 0; k < 4; ++k) {
                nA[k] = xrA[(g + 1) * 4 + k];
                nB[k] = xrB[(g + 1) * 4 + k];
            }
        }
        #pragma unroll
        for (int k = 0; k < 4; ++k) {
            float xsa[4] = {cA[k].x, cA[k].y, cA[k].z, cA[k].w};
            float xsb[4] = {cB[k].x, cB[k].y, cB[k].z, cB[k].w};
            #pragma unroll
            for (int e = 0; e < 4; ++e) {
                const int d = g * 16 + k * 4 + e;
                const float xA = xsa[e];
                const float xB = xsb[e];
                #pragma unroll
                for (int i = 0; i < V_; ++i) {
                    const float bi = Bs[d * V_ + i];
                    const float ai = As[d * V_ + i];
                    float eA = fmaf(xA, bi, -ai);
                    float eB = fmaf(xB, bi, -ai);
                    tA[i] = fmaf(eA, eA, tA[i]);
                    tB[i] = fmaf(eB, eB, tB[i]);
                }
            }
        }
        #pragma unroll
        for (int k = 0; k < 4; ++k) { cA[k] = nA[k]; cB[k] = nB[k]; }
    }

    // ---- softmax for both pixels
    float qA[V_], qB[V_];
    float mnA = 3.4e38f, mnB = 3.4e38f;
    #pragma unroll
    for (int i = 0; i < V_; ++i) { mnA = fminf(mnA, tA[i]); mnB = fminf(mnB, tB[i]); }
    float sumA = 0.f, sumB = 0.f;
    #pragma unroll
    for (int i = 0; i < V_; ++i) {
        qA[i] = __expf(-0.5f * (tA[i] - mnA));  sumA += qA[i];
        qB[i] = __expf(-0.5f * (tB[i] - mnB));  sumB += qB[i];
    }
    const float invA = 1.0f / sumA;
    const float invB = 1.0f / sumB;

    // Q rows to global (k4 needs them), float4 stores
    {
        float4* qoutA = (float4*)(Q + pA * V_);
        float4* qoutB = (float4*)(Q + pB * V_);
        #pragma unroll
        for (int j = 0; j < V_ / 4; ++j) {
            float4 oa, ob;
            oa.x = qA[4*j+0]*invA; oa.y = qA[4*j+1]*invA; oa.z = qA[4*j+2]*invA; oa.w = qA[4*j+3]*invA;
            ob.x = qB[4*j+0]*invB; ob.y = qB[4*j+1]*invB; ob.z = qB[4*j+2]*invB; ob.w = qB[4*j+3]*invB;
            qoutA[j] = oa;
            qoutB[j] = ob;
        }
    }

    // s accumulation into LDS (separate array -> no hazard with As/Bs)
    #pragma unroll
    for (int i = 0; i < V_; ++i) atomicAdd(&s_blk[i], qA[i]*invA + qB[i]*invB);

    // ================= phase 2: Q rows into LDS (reuse As/Bs storage) ======
    __syncthreads();   // all phase-1 As/Bs reads + s_blk atomics done
    {
        float4* ra = (float4*)(smem + (size_t)tid * QS_LD);
        float4* rb = (float4*)(smem + (size_t)(tid + 256) * QS_LD);
        #pragma unroll
        for (int j = 0; j < V_ / 4; ++j) {
            float4 oa, ob;
            oa.x = qA[4*j+0]*invA; oa.y = qA[4*j+1]*invA; oa.z = qA[4*j+2]*invA; oa.w = qA[4*j+3]*invA;
            ob.x = qB[4*j+0]*invB; ob.y = qB[4*j+1]*invB; ob.z = qB[4*j+2]*invB; ob.w = qB[4*j+3]*invB;
            ra[j] = oa;
            rb[j] = ob;
        }
    }
    if (tid < V_) atomicAdd(&s_out[tid], s_blk[tid]);
    __syncthreads();   // Qs visible to all

    // ================= phase 3: M[d,i] += sum_p X[p,d]*Q[p,i] ==============
    // thread t = d; coalesced x loads (256B/wave-inst), register
    // double-buffered 16-deep -> 16 loads in flight per wave.
    {
        float acc[V_];
        #pragma unroll
        for (int i = 0; i < V_; ++i) acc[i] = 0.f;

        const float* xb = X + p0 * D_ + tid;
        float xc[16], xn[16];
        #pragma unroll
        for (int k = 0; k < 16; ++k) xc[k] = xb[(size_t)k * D_];

        for (int g = 0; g < 32; ++g) {
            if (g < 31) {
                #pragma unroll
                for (int k = 0; k < 16; ++k)
                    xn[k] = xb[(size_t)((g + 1) * 16 + k) * D_];
            }
            #pragma unroll
            for (int k = 0; k < 16; ++k) {
                const float x = xc[k];
                const float4* q4 = (const float4*)(smem + (size_t)(g * 16 + k) * QS_LD);
                #pragma unroll
                for (int j = 0; j < 8; ++j) {
                    float4 q = q4[j];   // b128 broadcast (uniform addr)
                    acc[4*j+0] = fmaf(x, q.x, acc[4*j+0]);
                    acc[4*j+1] = fmaf(x, q.y, acc[4*j+1]);
                    acc[4*j+2] = fmaf(x, q.z, acc[4*j+2]);
                    acc[4*j+3] = fmaf(x, q.w, acc[4*j+3]);
                }
            }
            #pragma unroll
            for (int k = 0; k < 16; ++k) xc[k] = xn[k];
        }

        #pragma unroll
        for (int i = 0; i < V_; ++i) atomicAdd(&M[tid * V_ + i], acc[i]);
    }
}

// ---------------------------------------------------------------------------
// K3a: Z = (M - W*s)*iv/s ; Z /= sum_d Z^2 (per column) ; Adj = Z^T Z
// single block, 256 threads (thread = d).
// ---------------------------------------------------------------------------
__global__ __launch_bounds__(256) void k3a(const float* __restrict__ M,
                                           const float* __restrict__ s_in,
                                           const float* __restrict__ W,
                                           const float* __restrict__ var,
                                           float* __restrict__ Z,
                                           float* __restrict__ Adj)
{
    __shared__ float Zl[D_][V_];
    __shared__ float ss[V_];
    __shared__ float nrm[V_];
    const int t = threadIdx.x;
    if (t < V_) ss[t] = s_in[t];
    __syncthreads();

    #pragma unroll
    for (int i = 0; i < V_; ++i) {
        float iv = 1.0f / var[t*V_ + i];
        float z = (M[t*V_ + i] - W[t*V_ + i] * ss[i]) * iv / ss[i];
        Zl[t][i] = z;
    }
    __syncthreads();
    if (t < V_) {
        float n = 0.f;
        for (int d = 0; d < D_; ++d) { float z = Zl[d][t]; n = fmaf(z, z, n); }
        nrm[t] = n;
    }
    __syncthreads();
    #pragma unroll
    for (int i = 0; i < V_; ++i) {
        float z = Zl[t][i] / nrm[i];
        Zl[t][i] = z;
        Z[t*V_ + i] = z;
    }
    __syncthreads();
    // Adj: 1024 entries, 4 per thread
    #pragma unroll
    for (int e = 0; e < 4; ++e) {
        int idx = t*4 + e;
        int i = idx >> 5, j = idx & 31;
        float a = 0.f;
        for (int d = 0; d < D_; ++d) a = fmaf(Zl[d][i], Zl[d][j], a);
        Adj[idx] = a;
    }
}

// ---------------------------------------------------------------------------
// K3b: T[j] = sum_d Z[d,j]*weight[d,f] ; Zo[i,f] = relu(sum_j Adj[i,j]*T[j])
// one block per output column f.
// ---------------------------------------------------------------------------
__global__ __launch_bounds__(256) void k3b(const float* __restrict__ Z,
                                           const float* __restrict__ weight,
                                           const float* __restrict__ Adj,
                                           float* __restrict__ Zo)
{
    __shared__ float T[V_];
    const int t = threadIdx.x;
    const int f = blockIdx.x;
    if (t < V_) T[t] = 0.f;
    __syncthreads();
    const float wt = weight[t*OUTF_ + f];
    const float* zr = Z + t*V_;
    #pragma unroll
    for (int j = 0; j < V_; ++j) atomicAdd(&T[j], zr[j] * wt);
    __syncthreads();
    if (t < V_) {
        float o = 0.f;
        #pragma unroll
        for (int j = 0; j < V_; ++j) o = fmaf(Adj[t*V_ + j], T[j], o);
        Zo[t*OUTF_ + f] = fmaxf(o, 0.f);
    }
}

// ---------------------------------------------------------------------------
// K4: out[p,f] = sum_i Q[p,i] * Zo[i,f].  (unchanged from round 1)
// lane owns an f-quad (zc[4][32] in regs); wave w owns pixels [w*64,w*64+64);
// 8 ds_read_b128 broadcasts per pixel per block, coalesced float4 stores.
// ---------------------------------------------------------------------------
__global__ __launch_bounds__(256) void k4_out(const float* __restrict__ Q,
                                              const float* __restrict__ Zo,
                                              float* __restrict__ out)
{
    __shared__ __align__(16) float Qt[256][V_];   // 32 KB
    const int t  = threadIdx.x;
    const int fq = t & 63;          // f-quad index: f = fq*4 + k
    const int w  = t >> 6;          // wave id 0..3
    const size_t p0 = (size_t)blockIdx.x * 256;

    // Zo column quad into registers: zc[k][i] = Zo[i][fq*4+k]
    float zc[4][V_];
    #pragma unroll
    for (int i = 0; i < V_; ++i) {
        float4 z = ((const float4*)(Zo + i*OUTF_))[fq];   // coalesced, L2-hot
        zc[0][i] = z.x; zc[1][i] = z.y; zc[2][i] = z.z; zc[3][i] = z.w;
    }

    { // stage Q tile: 2048 float4 / 256 threads = 8 each, coalesced
        float4* dst = (float4*)(&Qt[0][0]);
        const float4* src = (const float4*)(Q + p0 * V_);
        #pragma unroll
        for (int k = 0; k < 8; ++k) dst[t + 256*k] = src[t + 256*k];
    }
    __syncthreads();

    float4* out4 = (float4*)(out + (p0 + (size_t)w*64) * OUTF_);
    #pragma unroll 2
    for (int pp = 0; pp < 64; ++pp) {
        const int p = w*64 + pp;
        const float4* q4 = (const float4*)(&Qt[p][0]);    // b128 broadcast
        float a0 = 0.f, a1 = 0.f, a2 = 0.f, a3 = 0.f;
        #pragma unroll
        for (int j = 0; j < 8; ++j) {
            float4 q = q4[j];
            a0 = fmaf(q.x, zc[0][4*j+0], a0);
            a1 = fmaf(q.x, zc[1][4*j+0], a1);
            a2 = fmaf(q.x, zc[2][4*j+0], a2);
            a3 = fmaf(q.x, zc[3][4*j+0], a3);
            a0 = fmaf(q.y, zc[0][4*j+1], a0);
            a1 = fmaf(q.y, zc[1][4*j+1], a1);
            a2 = fmaf(q.y, zc[2][4*j+1], a2);
            a3 = fmaf(q.y, zc[3][4*j+1], a3);
            a0 = fmaf(q.z, zc[0][4*j+2], a0);
            a1 = fmaf(q.z, zc[1][4*j+2], a1);
            a2 = fmaf(q.z, zc[2][4*j+2], a2);
            a3 = fmaf(q.z, zc[3][4*j+2], a3);
            a0 = fmaf(q.w, zc[0][4*j+3], a0);
            a1 = fmaf(q.w, zc[1][4*j+3], a1);
            a2 = fmaf(q.w, zc[2][4*j+3], a2);
            a3 = fmaf(q.w, zc[3][4*j+3], a3);
        }
        float4 o; o.x = a0; o.y = a1; o.z = a2; o.w = a3;
        out4[pp*64 + fq] = o;                             // coalesced 1KB/wave
    }
}

extern "C" void kernel_launch(void* const* d_in, const int* in_sizes, int n_in,
                              void* d_out, int out_size, void* d_ws, size_t ws_size,
                              hipStream_t stream)
{
    const float* X      = (const float*)d_in[0];
    const float* W      = (const float*)d_in[1];
    const float* var    = (const float*)d_in[2];
    const float* weight = (const float*)d_in[3];
    float* out = (float*)d_out;
    float* ws  = (float*)d_ws;

    float* Q   = ws;                         // HW_*V_ floats (32 MB)
    float* s   = Q   + (size_t)HW_ * V_;     // 32
    float* M   = s   + V_;                   // D_*V_
    float* Z   = M   + D_ * V_;              // D_*V_
    float* Adj = Z   + D_ * V_;              // V_*V_
    float* Zo  = Adj + V_ * V_;              // V_*OUTF_

    // zero the atomic accumulators (s and M are contiguous)
    hipMemsetAsync(s, 0, (V_ + D_*V_) * sizeof(float), stream);

    k12_fused<<<HW_/512, 256, 0, stream>>>(X, W, var, Q, s, M);
    k3a  <<<1,       256, 0, stream>>>(M, s, W, var, Z, Adj);
    k3b  <<<OUTF_,   256, 0, stream>>>(Z, weight, Adj, Zo);
    k4_out<<<HW_/256, 256, 0, stream>>>(Q, Zo, out);
}